// Round 8
// baseline (87.226 us; speedup 1.0000x reference)
//
#include <hip/hip_runtime.h>

typedef unsigned char u8;
typedef __attribute__((ext_vector_type(4))) float f32x4;
typedef __attribute__((ext_vector_type(4))) int i32x4;
typedef __attribute__((ext_vector_type(2))) long long2v;

// ---------- helpers ----------

__device__ __forceinline__ void gload_lds16(const void* g, void* l) {
    __builtin_amdgcn_global_load_lds(
        (const __attribute__((address_space(1))) void*)g,
        (__attribute__((address_space(3))) void*)l,
        16, 0, 0);
}

// ---------- prep: fp32 X -> fp8 e4m3 Xb (HW RNE cvt), sq from rounded values, zero out ----------

__global__ void krr_prep8(const float* __restrict__ X, u8* __restrict__ Xb,
                          float* __restrict__ sq, float* __restrict__ out) {
    const int rl  = threadIdx.x >> 4;
    const int l   = threadIdx.x & 15;
    const int row = blockIdx.x * 16 + rl;
    const float* src = X + (size_t)row * 256 + l * 16;

    float s = 0.f;
    int wv[4];
    #pragma unroll
    for (int c = 0; c < 4; ++c) {
        int pk = __builtin_amdgcn_cvt_pk_fp8_f32(src[c*4+0], src[c*4+1], 0, false);
        pk     = __builtin_amdgcn_cvt_pk_fp8_f32(src[c*4+2], src[c*4+3], pk, true);
        wv[c] = pk;
        float x0 = __builtin_amdgcn_cvt_f32_fp8(pk, 0);
        float x1 = __builtin_amdgcn_cvt_f32_fp8(pk, 1);
        float x2 = __builtin_amdgcn_cvt_f32_fp8(pk, 2);
        float x3 = __builtin_amdgcn_cvt_f32_fp8(pk, 3);
        s = fmaf(x0, x0, s);
        s = fmaf(x1, x1, s);
        s = fmaf(x2, x2, s);
        s = fmaf(x3, x3, s);
    }
    *reinterpret_cast<i32x4*>(Xb + (size_t)row * 256 + l * 16) =
        (i32x4){wv[0], wv[1], wv[2], wv[3]};

    s += __shfl_xor(s, 1, 16);
    s += __shfl_xor(s, 2, 16);
    s += __shfl_xor(s, 4, 16);
    s += __shfl_xor(s, 8, 16);
    if (l == 0) {
        sq[row]  = s;
        out[row] = 0.f;
    }
}

// ---------- symmetric fused kernel: fp8, FULL-K tile in LDS, one stage round-trip/tile ----------
// LDS: A[128 rows x 256 B] at 0, B at 32768 (offdiag only). Row = 16 chunks of 16B.
// Chunk slot sl holds global chunk sl ^ (r & 15)  (involution, applied on source and read).

__global__ __launch_bounds__(256, 2) void krr_symf(
    const u8* __restrict__ Xb, const float* __restrict__ sq,
    const float* __restrict__ alpha, float* __restrict__ out,
    int N)
{
    extern __shared__ __align__(16) u8 lds[];

    const int tid  = threadIdx.x;
    const int lane = tid & 63;
    const int w    = tid >> 6;          // 4 waves, 2x2
    const int wr   = (w >> 1) * 64;
    const int wc   = (w & 1) * 64;
    const int T    = N >> 7;

    // bijective XCD-aware swizzle (m204 general form)
    const int nwg = gridDim.x;
    const int linear = blockIdx.x;
    const int q8 = nwg >> 3, r8 = nwg & 7;
    const int xcd = linear & 7, rest = linear >> 3;
    const int swz = (xcd < r8 ? xcd * (q8 + 1) : r8 * (q8 + 1) + (xcd - r8) * q8) + rest;

    // triangular decode: swz -> (ti, tj), ti <= tj
    float Tf = (float)T + 0.5f;
    int ti = (int)(Tf - sqrtf(fmaxf(Tf * Tf - 2.0f * (float)swz, 0.f)));
    if (ti < 0) ti = 0;
    if (ti > T - 1) ti = T - 1;
    while ((ti + 1) * T - ((ti + 1) * ti) / 2 <= swz) ++ti;
    while (ti * T - (ti * (ti - 1)) / 2 > swz) --ti;
    const int tj = ti + (swz - (ti * T - (ti * (ti - 1)) / 2));
    const int rowBase = ti << 7;
    const int colBase = tj << 7;
    const bool offdiag = (ti != tj);
    const int bofs = offdiag ? 32768 : 0;

    // ---- single full-K stage: A panel (and B panel if offdiag) ----
    {
        #pragma unroll
        for (int it = 0; it < 8; ++it) {
            int idx = it * 256 + tid;            // 0..2047 chunk-slots
            int r = idx >> 4, sl = idx & 15;
            int gc = sl ^ (r & 15);              // pre-swizzled global chunk
            gload_lds16(&Xb[(size_t)(rowBase + r) * 256 + gc * 16], &lds[idx * 16]);
        }
        if (offdiag) {
            #pragma unroll
            for (int it = 0; it < 8; ++it) {
                int idx = it * 256 + tid;
                int r = idx >> 4, sl = idx & 15;
                int gc = sl ^ (r & 15);
                gload_lds16(&Xb[(size_t)(colBase + r) * 256 + gc * 16],
                            &lds[32768 + idx * 16]);
            }
        }
    }
    __syncthreads();

    // ---- 8 k-steps of fp8 16x16x32 MFMA, all from LDS ----
    f32x4 acc[4][4];
    #pragma unroll
    for (int m = 0; m < 4; ++m)
        #pragma unroll
        for (int n = 0; n < 4; ++n)
            acc[m][n] = (f32x4){0.f, 0.f, 0.f, 0.f};

    const int cg = lane >> 4;        // 0..3: 8B k-group
    const int hh = cg & 1;           // half within 16B chunk
    const int cs = cg >> 1;          // 16B chunk within 32B k-step
    const int rl = lane & 15;

    #pragma unroll
    for (int ks = 0; ks < 8; ++ks) {
        const int ch = 2 * ks + cs;               // logical chunk 0..15
        long a[4], b[4];
        #pragma unroll
        for (int m = 0; m < 4; ++m) {
            int r = wr + m * 16 + rl;
            long2v v = *reinterpret_cast<const long2v*>(
                &lds[r * 256 + ((ch ^ (r & 15)) << 4)]);
            a[m] = v[hh];
        }
        #pragma unroll
        for (int n = 0; n < 4; ++n) {
            int r = wc + n * 16 + rl;
            long2v v = *reinterpret_cast<const long2v*>(
                &lds[bofs + r * 256 + ((ch ^ (r & 15)) << 4)]);
            b[n] = v[hh];
        }
        #pragma unroll
        for (int m = 0; m < 4; ++m)
            #pragma unroll
            for (int n = 0; n < 4; ++n)
                acc[m][n] = __builtin_amdgcn_mfma_f32_16x16x32_fp8_fp8(
                    a[m], b[n], acc[m][n], 0, 0, 0);
    }

    // ---- fused symmetric epilogue (block end; atomics drain at endpgm) ----
    float sqc[4], alc[4];
    #pragma unroll
    for (int n = 0; n < 4; ++n) {
        int c = colBase + wc + n * 16 + rl;
        sqc[n] = sq[c];
        alc[n] = alpha[c];
    }
    float csum[4] = {0.f, 0.f, 0.f, 0.f};
    const int g4 = lane >> 4;
    #pragma unroll
    for (int m = 0; m < 4; ++m) {
        int r0 = rowBase + wr + m * 16 + g4 * 4;
        #pragma unroll
        for (int reg = 0; reg < 4; ++reg) {
            float sqr = sq[r0 + reg];
            float ar  = alpha[r0 + reg];
            float s = 0.f;
            #pragma unroll
            for (int n = 0; n < 4; ++n) {
                float d2 = sqr + sqc[n] - 2.0f * acc[m][n][reg];
                d2 = fmaxf(d2, 0.f);
                float k = __expf(-d2);
                s += k * alc[n];
                csum[n] = fmaf(k, ar, csum[n]);
            }
            s += __shfl_xor(s, 1, 16);
            s += __shfl_xor(s, 2, 16);
            s += __shfl_xor(s, 4, 16);
            s += __shfl_xor(s, 8, 16);
            if (rl == 0) atomicAdd(&out[r0 + reg], s);
        }
    }
    if (offdiag) {
        #pragma unroll
        for (int n = 0; n < 4; ++n) {
            csum[n] += __shfl_xor(csum[n], 16, 64);
            csum[n] += __shfl_xor(csum[n], 32, 64);
            if (g4 == 0)
                atomicAdd(&out[colBase + wc + n * 16 + rl], csum[n]);
        }
    }
}

// ---------- fallback: honest fp32, slow ----------

__global__ void krr_naive(const float* __restrict__ X, const float* __restrict__ alpha,
                          float* __restrict__ out, int N, int D) {
    __shared__ float xi[256];
    const int i = blockIdx.x;
    const int t = threadIdx.x;
    for (int k = t; k < D; k += blockDim.x) xi[k] = X[(size_t)i * D + k];
    __syncthreads();
    float s = 0.f;
    for (int j = t; j < N; j += blockDim.x) {
        float d2 = 0.f;
        const float* xj = &X[(size_t)j * D];
        for (int k = 0; k < D; ++k) {
            float d = xi[k] - xj[k];
            d2 = fmaf(d, d, d2);
        }
        s += __expf(-fmaxf(d2, 0.f)) * alpha[j];
    }
    #pragma unroll
    for (int off = 32; off > 0; off >>= 1) s += __shfl_xor(s, off, 64);
    __shared__ float red[4];
    const int lane = t & 63, w = t >> 6;
    if (lane == 0) red[w] = s;
    __syncthreads();
    if (t == 0) out[i] = red[0] + red[1] + red[2] + red[3];
}

// ---------- launch ----------

extern "C" void kernel_launch(void* const* d_in, const int* in_sizes, int n_in,
                              void* d_out, int out_size, void* d_ws, size_t ws_size,
                              hipStream_t stream) {
    const float* X     = (const float*)d_in[0];
    const float* alpha = (const float*)d_in[1];
    float* out = (float*)d_out;

    const int N = in_sizes[1];           // 8192
    const int D = in_sizes[0] / N;       // 256

    size_t xb_bytes = (size_t)N * D;     // fp8: 1 B/elem
    size_t need     = xb_bytes + (size_t)N * sizeof(float);

    const int T = N >> 7;
    const int ntiles = T * (T + 1) / 2;  // 2080 for N=8192

    bool shapes_ok = (D == 256) && (N % 128) == 0 && (N % 16) == 0 && (N == out_size);

    hipError_t e = hipFuncSetAttribute(
        reinterpret_cast<const void*>(krr_symf),
        hipFuncAttributeMaxDynamicSharedMemorySize, 65536);

    if (ws_size >= need && shapes_ok && e == hipSuccess) {
        u8*    Xb = (u8*)d_ws;
        float* sq = (float*)((char*)d_ws + xb_bytes);
        krr_prep8<<<N / 16, 256, 0, stream>>>(X, Xb, sq, out);
        krr_symf<<<ntiles, 256, 65536, stream>>>(Xb, sq, alpha, out, N);
    } else {
        (void)hipMemsetAsync(d_out, 0, (size_t)out_size * sizeof(float), stream);
        krr_naive<<<N, 256, 0, stream>>>(X, alpha, out, N, D);
    }
}

// Round 9
// 61.209 us; speedup vs baseline: 1.4250x; 1.4250x over previous
//
#include <hip/hip_runtime.h>

typedef unsigned char u8;
typedef __attribute__((ext_vector_type(4))) float f32x4;
typedef __attribute__((ext_vector_type(4))) int i32x4;

#define RSTRIDE 264   // 256 B fp8 row + 8 B pad -> conflict-free b64 lanes

// ---------- prep: fp32 X -> fp8 e4m3 Xb (HW RNE cvt), sq from rounded values, zero out ----------

__global__ void krr_prep8(const float* __restrict__ X, u8* __restrict__ Xb,
                          float* __restrict__ sq, float* __restrict__ out) {
    const int rl  = threadIdx.x >> 4;
    const int l   = threadIdx.x & 15;
    const int row = blockIdx.x * 16 + rl;
    const float* src = X + (size_t)row * 256 + l * 16;

    float s = 0.f;
    int wv[4];
    #pragma unroll
    for (int c = 0; c < 4; ++c) {
        int pk = __builtin_amdgcn_cvt_pk_fp8_f32(src[c*4+0], src[c*4+1], 0, false);
        pk     = __builtin_amdgcn_cvt_pk_fp8_f32(src[c*4+2], src[c*4+3], pk, true);
        wv[c] = pk;
        float x0 = __builtin_amdgcn_cvt_f32_fp8(pk, 0);
        float x1 = __builtin_amdgcn_cvt_f32_fp8(pk, 1);
        float x2 = __builtin_amdgcn_cvt_f32_fp8(pk, 2);
        float x3 = __builtin_amdgcn_cvt_f32_fp8(pk, 3);
        s = fmaf(x0, x0, s);
        s = fmaf(x1, x1, s);
        s = fmaf(x2, x2, s);
        s = fmaf(x3, x3, s);
    }
    *reinterpret_cast<i32x4*>(Xb + (size_t)row * 256 + l * 16) =
        (i32x4){wv[0], wv[1], wv[2], wv[3]};

    s += __shfl_xor(s, 1, 16);
    s += __shfl_xor(s, 2, 16);
    s += __shfl_xor(s, 4, 16);
    s += __shfl_xor(s, 8, 16);
    if (l == 0) {
        sq[row]  = s;
        out[row] = 0.f;
    }
}

// ---------- big-tile symmetric kernel: 256x256 tile, full K=256 in LDS, one round-trip ----------
// 1024 threads = 16 waves (4x4), wave-tile 64x64, fp8 16x16x32 MFMA.
// LDS rows padded to 264 B; reg-staged ds_write_b64 (padding needs reg staging).

__global__ __launch_bounds__(1024) void krr_big(
    const u8* __restrict__ Xb, const float* __restrict__ sq,
    const float* __restrict__ alpha, float* __restrict__ out, int N)
{
    extern __shared__ __align__(16) u8 lds[];

    const int tid  = threadIdx.x;
    const int lane = tid & 63;
    const int w    = tid >> 6;           // 0..15
    const int wr   = (w >> 2) * 64;
    const int wc   = (w & 3) * 64;
    const int T    = N >> 8;             // 256-row tiles
    const int nOff = T * (T - 1) / 2;    // off-diag pairs first, diag last

    int ti, tj;
    if ((int)blockIdx.x < nOff) {
        const int t = blockIdx.x;
        float Tf = (float)T - 0.5f;
        ti = (int)(Tf - sqrtf(fmaxf(Tf * Tf - 2.0f * (float)t, 0.f)));
        if (ti < 0) ti = 0;
        if (ti > T - 2) ti = T - 2;
        // S(i) = i*T - i(i+1)/2 = first linear index of row i
        while ((ti + 1) * T - ((ti + 1) * (ti + 2)) / 2 <= t) ++ti;
        while (ti * T - (ti * (ti + 1)) / 2 > t) --ti;
        tj = ti + 1 + (t - (ti * T - (ti * (ti + 1)) / 2));
    } else {
        ti = tj = blockIdx.x - nOff;
    }
    const int rowBase = ti << 8;
    const int colBase = tj << 8;
    const bool offdiag = (ti != tj);

    // ---- single stage: A panel rows [0,256), B panel rows [256,512) (offdiag only) ----
    {
        i32x4 regs[8];
        const int nit = offdiag ? 8 : 4;
        #pragma unroll
        for (int it = 0; it < 8; ++it) {
            if (it < nit) {
                int idx = it * 1024 + tid;           // 0..8191 chunk id
                int p   = idx >> 12;                 // 0=A, 1=B
                int r   = (idx >> 4) & 255;
                int c   = idx & 15;
                int gr  = (p ? colBase : rowBase) + r;
                regs[it] = *reinterpret_cast<const i32x4*>(&Xb[(size_t)gr * 256 + c * 16]);
            }
        }
        #pragma unroll
        for (int it = 0; it < 8; ++it) {
            if (it < nit) {
                int idx = it * 1024 + tid;
                int p   = idx >> 12;
                int r   = (idx >> 4) & 255;
                int c   = idx & 15;
                u8* dst = &lds[(size_t)(p * 256 + r) * RSTRIDE + c * 16];
                *reinterpret_cast<long*>(dst)     = ((const long*)&regs[it])[0];
                *reinterpret_cast<long*>(dst + 8) = ((const long*)&regs[it])[1];
            }
        }
    }
    __syncthreads();

    // ---- 8 k-steps of fp8 16x16x32 MFMA, all operands resident ----
    f32x4 acc[4][4];
    #pragma unroll
    for (int m = 0; m < 4; ++m)
        #pragma unroll
        for (int n = 0; n < 4; ++n)
            acc[m][n] = (f32x4){0.f, 0.f, 0.f, 0.f};

    const int g  = lane >> 4;            // k-group: holds k-bytes [g*8, g*8+8) of each 32-k-step
    const int rl = lane & 15;
    const u8* Abase = &lds[(size_t)(wr + rl) * RSTRIDE + g * 8];
    const u8* Bbase = &lds[(size_t)((offdiag ? 256 : 0) + wc + rl) * RSTRIDE + g * 8];

    #pragma unroll
    for (int ks = 0; ks < 8; ++ks) {
        long a[4], b[4];
        #pragma unroll
        for (int m = 0; m < 4; ++m)
            a[m] = *reinterpret_cast<const long*>(Abase + (size_t)m * 16 * RSTRIDE + ks * 32);
        #pragma unroll
        for (int n = 0; n < 4; ++n)
            b[n] = *reinterpret_cast<const long*>(Bbase + (size_t)n * 16 * RSTRIDE + ks * 32);
        #pragma unroll
        for (int m = 0; m < 4; ++m)
            #pragma unroll
            for (int n = 0; n < 4; ++n)
                acc[m][n] = __builtin_amdgcn_mfma_f32_16x16x32_fp8_fp8(
                    a[m], b[n], acc[m][n], 0, 0, 0);
    }

    // ---- fused symmetric epilogue: d2 -> exp -> *alpha; row path always, col path offdiag ----
    float sqc[4], alc[4];
    #pragma unroll
    for (int n = 0; n < 4; ++n) {
        int c = colBase + wc + n * 16 + rl;
        sqc[n] = sq[c];
        alc[n] = alpha[c];
    }
    float csum[4] = {0.f, 0.f, 0.f, 0.f};
    #pragma unroll
    for (int m = 0; m < 4; ++m) {
        int r0 = rowBase + wr + m * 16 + g * 4;
        #pragma unroll
        for (int reg = 0; reg < 4; ++reg) {
            float sqr = sq[r0 + reg];
            float ar  = alpha[r0 + reg];
            float s = 0.f;
            #pragma unroll
            for (int n = 0; n < 4; ++n) {
                float d2 = sqr + sqc[n] - 2.0f * acc[m][n][reg];
                d2 = fmaxf(d2, 0.f);
                float k = __expf(-d2);
                s += k * alc[n];
                csum[n] = fmaf(k, ar, csum[n]);
            }
            s += __shfl_xor(s, 1, 16);
            s += __shfl_xor(s, 2, 16);
            s += __shfl_xor(s, 4, 16);
            s += __shfl_xor(s, 8, 16);
            if (rl == 0) atomicAdd(&out[r0 + reg], s);
        }
    }
    if (offdiag) {
        #pragma unroll
        for (int n = 0; n < 4; ++n) {
            csum[n] += __shfl_xor(csum[n], 16, 64);
            csum[n] += __shfl_xor(csum[n], 32, 64);
            if (g == 0)
                atomicAdd(&out[colBase + wc + n * 16 + rl], csum[n]);
        }
    }
}

// ---------- fallback: honest fp32, slow ----------

__global__ void krr_naive(const float* __restrict__ X, const float* __restrict__ alpha,
                          float* __restrict__ out, int N, int D) {
    __shared__ float xi[256];
    const int i = blockIdx.x;
    const int t = threadIdx.x;
    for (int k = t; k < D; k += blockDim.x) xi[k] = X[(size_t)i * D + k];
    __syncthreads();
    float s = 0.f;
    for (int j = t; j < N; j += blockDim.x) {
        float d2 = 0.f;
        const float* xj = &X[(size_t)j * D];
        for (int k = 0; k < D; ++k) {
            float d = xi[k] - xj[k];
            d2 = fmaf(d, d, d2);
        }
        s += __expf(-fmaxf(d2, 0.f)) * alpha[j];
    }
    #pragma unroll
    for (int off = 32; off > 0; off >>= 1) s += __shfl_xor(s, off, 64);
    __shared__ float red[4];
    const int lane = t & 63, w = t >> 6;
    if (lane == 0) red[w] = s;
    __syncthreads();
    if (t == 0) out[i] = red[0] + red[1] + red[2] + red[3];
}

// ---------- launch ----------

extern "C" void kernel_launch(void* const* d_in, const int* in_sizes, int n_in,
                              void* d_out, int out_size, void* d_ws, size_t ws_size,
                              hipStream_t stream) {
    const float* X     = (const float*)d_in[0];
    const float* alpha = (const float*)d_in[1];
    float* out = (float*)d_out;

    const int N = in_sizes[1];           // 8192
    const int D = in_sizes[0] / N;       // 256

    size_t xb_bytes = (size_t)N * D;     // fp8: 1 B/elem
    size_t need     = xb_bytes + (size_t)N * sizeof(float);

    const int T = N >> 8;                // 32
    const int ntiles = T * (T + 1) / 2;  // 528

    const size_t LDS_BYTES = (size_t)512 * RSTRIDE;  // 135168

    bool shapes_ok = (D == 256) && (N % 256) == 0 && (N == out_size) && T >= 2;

    hipError_t e = hipFuncSetAttribute(
        reinterpret_cast<const void*>(krr_big),
        hipFuncAttributeMaxDynamicSharedMemorySize, (int)LDS_BYTES);

    if (ws_size >= need && shapes_ok && e == hipSuccess) {
        u8*    Xb = (u8*)d_ws;
        float* sq = (float*)((char*)d_ws + xb_bytes);
        krr_prep8<<<N / 16, 256, 0, stream>>>(X, Xb, sq, out);
        krr_big<<<ntiles, 1024, LDS_BYTES, stream>>>(Xb, sq, alpha, out, N);
    } else {
        (void)hipMemsetAsync(d_out, 0, (size_t)out_size * sizeof(float), stream);
        krr_naive<<<N, 256, 0, stream>>>(X, alpha, out, N, D);
    }
}

// Round 10
// 45.803 us; speedup vs baseline: 1.9044x; 1.3364x over previous
//
#include <hip/hip_runtime.h>

typedef unsigned char u8;
typedef __attribute__((ext_vector_type(4))) float f32x4;
typedef __attribute__((ext_vector_type(4))) int i32x4;

#define RSTRIDE 264   // 256 B fp8 row + 8 B pad

// ---------- prep: fp32 X -> fp8 e4m3 Xb (HW RNE cvt), sq from rounded values ----------

__global__ void krr_prep8(const float* __restrict__ X, u8* __restrict__ Xb,
                          float* __restrict__ sq) {
    const int rl  = threadIdx.x >> 4;
    const int l   = threadIdx.x & 15;
    const int row = blockIdx.x * 16 + rl;
    const float* src = X + (size_t)row * 256 + l * 16;

    float s = 0.f;
    int wv[4];
    #pragma unroll
    for (int c = 0; c < 4; ++c) {
        int pk = __builtin_amdgcn_cvt_pk_fp8_f32(src[c*4+0], src[c*4+1], 0, false);
        pk     = __builtin_amdgcn_cvt_pk_fp8_f32(src[c*4+2], src[c*4+3], pk, true);
        wv[c] = pk;
        float x0 = __builtin_amdgcn_cvt_f32_fp8(pk, 0);
        float x1 = __builtin_amdgcn_cvt_f32_fp8(pk, 1);
        float x2 = __builtin_amdgcn_cvt_f32_fp8(pk, 2);
        float x3 = __builtin_amdgcn_cvt_f32_fp8(pk, 3);
        s = fmaf(x0, x0, s);
        s = fmaf(x1, x1, s);
        s = fmaf(x2, x2, s);
        s = fmaf(x3, x3, s);
    }
    *reinterpret_cast<i32x4*>(Xb + (size_t)row * 256 + l * 16) =
        (i32x4){wv[0], wv[1], wv[2], wv[3]};

    s += __shfl_xor(s, 1, 16);
    s += __shfl_xor(s, 2, 16);
    s += __shfl_xor(s, 4, 16);
    s += __shfl_xor(s, 8, 16);
    if (l == 0) sq[row] = s;
}

// ---------- big-tile symmetric kernel: 256x256, full K in LDS, NO ATOMICS ----------
// Partials: P[chunk][row]; row path of (ti,tj) -> P[tj][ti-rows], col path -> P[ti][tj-rows],
// diag -> P[ti][ti-rows]. Each entry written by exactly one block (plain stores).

__global__ __launch_bounds__(1024) void krr_big(
    const u8* __restrict__ Xb, const float* __restrict__ sq,
    const float* __restrict__ alpha, float* __restrict__ P, int N)
{
    extern __shared__ __align__(16) u8 lds[];

    const int tid  = threadIdx.x;
    const int lane = tid & 63;
    const int w    = tid >> 6;           // 0..15, 4x4 wave grid
    const int wr   = (w >> 2) * 64;
    const int wc   = (w & 3) * 64;
    const int T    = N >> 8;
    const int nOff = T * (T - 1) / 2;    // off-diag blocks first, diag (half-work) last

    int ti, tj;
    if ((int)blockIdx.x < nOff) {
        const int t = blockIdx.x;
        float Tf = (float)T - 0.5f;
        ti = (int)(Tf - sqrtf(fmaxf(Tf * Tf - 2.0f * (float)t, 0.f)));
        if (ti < 0) ti = 0;
        if (ti > T - 2) ti = T - 2;
        while ((ti + 1) * T - ((ti + 1) * (ti + 2)) / 2 <= t) ++ti;
        while (ti * T - (ti * (ti + 1)) / 2 > t) --ti;
        tj = ti + 1 + (t - (ti * T - (ti * (ti + 1)) / 2));
    } else {
        ti = tj = blockIdx.x - nOff;
    }
    const int rowBase = ti << 8;
    const int colBase = tj << 8;
    const bool offdiag = (ti != tj);

    // ---- single stage: A rows [0,256), B rows [256,512) (offdiag only) ----
    {
        i32x4 regs[8];
        const int nit = offdiag ? 8 : 4;
        #pragma unroll
        for (int it = 0; it < 8; ++it) {
            if (it < nit) {
                int idx = it * 1024 + tid;
                int p   = idx >> 12;
                int r   = (idx >> 4) & 255;
                int c   = idx & 15;
                int gr  = (p ? colBase : rowBase) + r;
                regs[it] = *reinterpret_cast<const i32x4*>(&Xb[(size_t)gr * 256 + c * 16]);
            }
        }
        #pragma unroll
        for (int it = 0; it < 8; ++it) {
            if (it < nit) {
                int idx = it * 1024 + tid;
                int p   = idx >> 12;
                int r   = (idx >> 4) & 255;
                int c   = idx & 15;
                u8* dst = &lds[(size_t)(p * 256 + r) * RSTRIDE + c * 16];
                *reinterpret_cast<long*>(dst)     = ((const long*)&regs[it])[0];
                *reinterpret_cast<long*>(dst + 8) = ((const long*)&regs[it])[1];
            }
        }
    }
    __syncthreads();

    // ---- 8 k-steps of fp8 16x16x32 MFMA ----
    f32x4 acc[4][4];
    #pragma unroll
    for (int m = 0; m < 4; ++m)
        #pragma unroll
        for (int n = 0; n < 4; ++n)
            acc[m][n] = (f32x4){0.f, 0.f, 0.f, 0.f};

    const int g  = lane >> 4;
    const int rl = lane & 15;
    const u8* Abase = &lds[(size_t)(wr + rl) * RSTRIDE + g * 8];
    const u8* Bbase = &lds[(size_t)((offdiag ? 256 : 0) + wc + rl) * RSTRIDE + g * 8];

    #pragma unroll
    for (int ks = 0; ks < 8; ++ks) {
        long a[4], b[4];
        #pragma unroll
        for (int m = 0; m < 4; ++m)
            a[m] = *reinterpret_cast<const long*>(Abase + (size_t)m * 16 * RSTRIDE + ks * 32);
        #pragma unroll
        for (int n = 0; n < 4; ++n)
            b[n] = *reinterpret_cast<const long*>(Bbase + (size_t)n * 16 * RSTRIDE + ks * 32);
        #pragma unroll
        for (int m = 0; m < 4; ++m)
            #pragma unroll
            for (int n = 0; n < 4; ++n)
                acc[m][n] = __builtin_amdgcn_mfma_f32_16x16x32_fp8_fp8(
                    a[m], b[n], acc[m][n], 0, 0, 0);
    }

    // ---- epilogue: d2 -> exp -> *alpha; reduce in registers ----
    float sqc[4], alc[4];
    #pragma unroll
    for (int n = 0; n < 4; ++n) {
        int c = colBase + wc + n * 16 + rl;
        sqc[n] = sq[c];
        alc[n] = alpha[c];
    }
    float csum[4] = {0.f, 0.f, 0.f, 0.f};
    float rowKeep[4] = {0.f, 0.f, 0.f, 0.f};
    #pragma unroll
    for (int m = 0; m < 4; ++m) {
        int r0 = rowBase + wr + m * 16 + g * 4;
        #pragma unroll
        for (int reg = 0; reg < 4; ++reg) {
            float sqr = sq[r0 + reg];
            float ar  = alpha[r0 + reg];
            float s = 0.f;
            #pragma unroll
            for (int n = 0; n < 4; ++n) {
                float d2 = sqr + sqc[n] - 2.0f * acc[m][n][reg];
                d2 = fmaxf(d2, 0.f);
                float k = __expf(-d2);
                s += k * alc[n];
                csum[n] = fmaf(k, ar, csum[n]);
            }
            s += __shfl_xor(s, 1, 16);
            s += __shfl_xor(s, 2, 16);
            s += __shfl_xor(s, 4, 16);
            s += __shfl_xor(s, 8, 16);   // s uniform over 16-lane group
            if (reg == rl) rowKeep[m] = s;   // lanes rl<4 hold reg==rl
        }
    }
    #pragma unroll
    for (int n = 0; n < 4; ++n) {
        csum[n] += __shfl_xor(csum[n], 16, 64);
        csum[n] += __shfl_xor(csum[n], 32, 64);   // uniform over wave
    }

    // ---- cross-wave reduction in LDS (compute done; safe to overwrite after sync) ----
    __syncthreads();
    float* ldsR = (float*)lds;          // [4 wc-groups][256 rows]
    float* ldsC = ldsR + 1024;          // [4 wr-groups][256 cols]
    if (rl < 4) {
        #pragma unroll
        for (int m = 0; m < 4; ++m)
            ldsR[(w & 3) * 256 + wr + m * 16 + g * 4 + rl] = rowKeep[m];
    }
    ldsC[(w >> 2) * 256 + wc + g * 16 + rl] = csum[g];
    __syncthreads();

    if (tid < 256) {
        float v = ldsR[tid] + ldsR[256 + tid] + ldsR[512 + tid] + ldsR[768 + tid];
        P[(size_t)tj * N + rowBase + tid] = v;
    } else if (tid < 512 && offdiag) {
        int r = tid - 256;
        float v = ldsC[r] + ldsC[256 + r] + ldsC[512 + r] + ldsC[768 + r];
        P[(size_t)ti * N + colBase + r] = v;
    }
}

// ---------- final reduce: out[i] = sum_c P[c][i] (no atomics anywhere) ----------

__global__ void krr_reduce(const float* __restrict__ P, float* __restrict__ out,
                           int N, int T) {
    const int i = blockIdx.x * 256 + threadIdx.x;
    float s = 0.f;
    #pragma unroll 8
    for (int c = 0; c < T; ++c) s += P[(size_t)c * N + i];
    out[i] = s;
}

// ---------- fallback: honest fp32, slow ----------

__global__ void krr_naive(const float* __restrict__ X, const float* __restrict__ alpha,
                          float* __restrict__ out, int N, int D) {
    __shared__ float xi[256];
    const int i = blockIdx.x;
    const int t = threadIdx.x;
    for (int k = t; k < D; k += blockDim.x) xi[k] = X[(size_t)i * D + k];
    __syncthreads();
    float s = 0.f;
    for (int j = t; j < N; j += blockDim.x) {
        float d2 = 0.f;
        const float* xj = &X[(size_t)j * D];
        for (int k = 0; k < D; ++k) {
            float d = xi[k] - xj[k];
            d2 = fmaf(d, d, d2);
        }
        s += __expf(-fmaxf(d2, 0.f)) * alpha[j];
    }
    #pragma unroll
    for (int off = 32; off > 0; off >>= 1) s += __shfl_xor(s, off, 64);
    __shared__ float red[4];
    const int lane = t & 63, w = t >> 6;
    if (lane == 0) red[w] = s;
    __syncthreads();
    if (t == 0) out[i] = red[0] + red[1] + red[2] + red[3];
}

// ---------- launch ----------

extern "C" void kernel_launch(void* const* d_in, const int* in_sizes, int n_in,
                              void* d_out, int out_size, void* d_ws, size_t ws_size,
                              hipStream_t stream) {
    const float* X     = (const float*)d_in[0];
    const float* alpha = (const float*)d_in[1];
    float* out = (float*)d_out;

    const int N = in_sizes[1];           // 8192
    const int D = in_sizes[0] / N;       // 256

    size_t xb_bytes = (size_t)N * D;                 // 2 MiB fp8
    size_t sq_bytes = (size_t)N * sizeof(float);     // 32 KiB
    const int T = N >> 8;                            // 32
    size_t p_bytes  = (size_t)T * N * sizeof(float); // 1 MiB
    size_t need     = xb_bytes + sq_bytes + p_bytes;

    const int ntiles = T * (T + 1) / 2;  // 528
    const size_t LDS_BYTES = (size_t)512 * RSTRIDE;  // 135168

    bool shapes_ok = (D == 256) && (N % 256) == 0 && (N == out_size) && T >= 2;

    hipError_t e = hipFuncSetAttribute(
        reinterpret_cast<const void*>(krr_big),
        hipFuncAttributeMaxDynamicSharedMemorySize, (int)LDS_BYTES);

    if (ws_size >= need && shapes_ok && e == hipSuccess) {
        u8*    Xb = (u8*)d_ws;
        float* sq = (float*)((char*)d_ws + xb_bytes);
        float* P  = (float*)((char*)d_ws + xb_bytes + sq_bytes);
        krr_prep8<<<N / 16, 256, 0, stream>>>(X, Xb, sq);
        krr_big<<<ntiles, 1024, LDS_BYTES, stream>>>(Xb, sq, alpha, P, N);
        krr_reduce<<<N / 256, 256, 0, stream>>>(P, out, N, T);
    } else {
        (void)hipMemsetAsync(d_out, 0, (size_t)out_size * sizeof(float), stream);
        krr_naive<<<N, 256, 0, stream>>>(X, alpha, out, N, D);
    }
}